// Round 3
// baseline (1447.540 us; speedup 1.0000x reference)
//
#include <hip/hip_runtime.h>
#include <hip/hip_cooperative_groups.h>

namespace cg = cooperative_groups;

#define NN 50000
#define TT 10
#define EE 1000000
#define GRID_BLOCKS 256
#define BLOCK 512
#define GSIZE (GRID_BLOCKS * BLOCK)   // 131072 threads

__device__ __forceinline__ float sigmoidf_(float v) { return 1.0f / (1.0f + __expf(-v)); }
__device__ __forceinline__ float reluf_(float v) { return v > 0.0f ? v : 0.0f; }

// MLP1: feat[9] -> relu(9x32) -> relu(32x32) -> sigmoid(32x1)
__device__ __forceinline__ float mlp1_eval(const float* feat,
                                           const float* s_w1, const float* s_b1,
                                           const float* s_w2, const float* s_b2,
                                           const float* s_w3, float s_b3) {
    float h1[32];
#pragma unroll
    for (int j = 0; j < 32; ++j) {
        float acc = s_b1[j];
#pragma unroll
        for (int i = 0; i < 9; ++i) acc += feat[i] * s_w1[i * 32 + j];
        h1[j] = reluf_(acc);
    }
    float acc3 = s_b3;
#pragma unroll
    for (int j2 = 0; j2 < 32; ++j2) {
        float acc = s_b2[j2];
#pragma unroll
        for (int i = 0; i < 32; ++i) acc += h1[i] * s_w2[i * 32 + j2];
        acc3 += reluf_(acc) * s_w3[j2];
    }
    return sigmoidf_(acc3);
}

__global__ void __launch_bounds__(BLOCK, 2)
fused_kernel(const float* __restrict__ x, const int* __restrict__ ei,
             const float* __restrict__ ea,
             const float* __restrict__ m1w1, const float* __restrict__ m1b1,
             const float* __restrict__ m1w2, const float* __restrict__ m1b2,
             const float* __restrict__ m1w3, const float* __restrict__ m1b3,
             const float* __restrict__ m2w1, const float* __restrict__ m2b1,
             const float* __restrict__ m2w2, const float* __restrict__ m2b2,
             const float* __restrict__ ow1, const float* __restrict__ ob1,
             const float* __restrict__ ow2, const float* __restrict__ ob2,
             float* __restrict__ out,
             float* __restrict__ msg_base, float* __restrict__ agg,
             float* __restrict__ xa, float* __restrict__ xb,
             float* __restrict__ eaT, int fast_x, int fast_ea) {
    __shared__ float s_w1[288], s_b1[32], s_w2[1024], s_b2[32], s_w3[32];
    __shared__ float s_m2w1[320], s_m2b1[32], s_m2w2[256], s_m2b2[8];
    __shared__ float s_ow1[128], s_ob1[16], s_ow2[16];
    __shared__ float s_b3s, s_ob2s;

    const int tid = threadIdx.x;
    for (int i = tid; i < 288; i += BLOCK) s_w1[i] = m1w1[i];
    for (int i = tid; i < 1024; i += BLOCK) s_w2[i] = m1w2[i];
    for (int i = tid; i < 320; i += BLOCK) s_m2w1[i] = m2w1[i];
    for (int i = tid; i < 256; i += BLOCK) s_m2w2[i] = m2w2[i];
    for (int i = tid; i < 128; i += BLOCK) s_ow1[i] = ow1[i];
    if (tid < 32) {
        s_b1[tid] = m1b1[tid];
        s_b2[tid] = m1b2[tid];
        s_w3[tid] = m1w3[tid];
        s_m2b1[tid] = m2b1[tid];
    }
    if (tid < 16) { s_ob1[tid] = ob1[tid]; s_ow2[tid] = ow2[tid]; }
    if (tid < 8) s_m2b2[tid] = m2b2[tid];
    if (tid == 0) { s_b3s = m1b3[0]; s_ob2s = ob2[0]; }
    __syncthreads();

    cg::grid_group grid = cg::this_grid();
    const int gid = blockIdx.x * BLOCK + tid;

    // ---- Phase A: transposes + per-node init ----
    if (fast_x) {
        for (int n = gid; n < NN; n += GSIZE) {
            const float4* xp = reinterpret_cast<const float4*>(x + (size_t)n * 20);
            float4 v0 = xp[0], v1 = xp[1], v2 = xp[2], v3 = xp[3], v4 = xp[4];
            float vv[20] = {v0.x, v0.y, v0.z, v0.w, v1.x, v1.y, v1.z, v1.w,
                            v2.x, v2.y, v2.z, v2.w, v3.x, v3.y, v3.z, v3.w,
                            v4.x, v4.y, v4.z, v4.w};
#pragma unroll
            for (int t = 0; t < TT; ++t) {
                xa[t * NN + n] = vv[2 * t];
                xb[t * NN + n] = vv[2 * t + 1];
            }
        }
    }
    if (fast_ea) {
        for (int e = gid; e < EE; e += GSIZE) {
            const float2* p = reinterpret_cast<const float2*>(ea + (size_t)e * TT);
            float2 a0 = p[0], a1 = p[1], a2 = p[2], a3 = p[3], a4 = p[4];
            eaT[0 * EE + e] = a0.x; eaT[1 * EE + e] = a0.y;
            eaT[2 * EE + e] = a1.x; eaT[3 * EE + e] = a1.y;
            eaT[4 * EE + e] = a2.x; eaT[5 * EE + e] = a2.y;
            eaT[6 * EE + e] = a3.x; eaT[7 * EE + e] = a3.y;
            eaT[8 * EE + e] = a4.x; eaT[9 * EE + e] = a4.y;
        }
    }

    float hid[8];
#pragma unroll
    for (int k = 0; k < 8; ++k) hid[k] = 0.0f;

    if (gid < NN) {
        float feat[9];
        feat[0] = x[(size_t)gid * 20];     // x[n][0][0]
#pragma unroll
        for (int k = 0; k < 8; ++k) feat[1 + k] = 0.0f;
        msg_base[gid] = mlp1_eval(feat, s_w1, s_b1, s_w2, s_b2, s_w3, s_b3s);
        agg[gid] = 0.0f;
    }
    grid.sync();

    // ---- Frame loop ----
    for (int t = 0; t < TT; ++t) {
        // Edge phase: 8 edges per thread (2 rounds x int4/float4)
        const int* srcp = ei + (size_t)t * EE;
        const int* dstp = ei + (size_t)TT * EE + (size_t)t * EE;
        if (fast_ea) {
            const float* eat = eaT + (size_t)t * EE;
#pragma unroll
            for (int r = 0; r < 2; ++r) {
                int e = (gid + r * GSIZE) * 4;
                if (e < EE) {
                    int4 s4 = *reinterpret_cast<const int4*>(srcp + e);
                    int4 d4 = *reinterpret_cast<const int4*>(dstp + e);
                    float4 a4 = *reinterpret_cast<const float4*>(eat + e);
                    float m0 = msg_base[s4.x] * a4.x;
                    float m1 = msg_base[s4.y] * a4.y;
                    float m2 = msg_base[s4.z] * a4.z;
                    float m3 = msg_base[s4.w] * a4.w;
                    atomicAdd(agg + d4.x, m0);
                    atomicAdd(agg + d4.y, m1);
                    atomicAdd(agg + d4.z, m2);
                    atomicAdd(agg + d4.w, m3);
                }
            }
        } else {
#pragma unroll
            for (int r = 0; r < 2; ++r) {
                int e = (gid + r * GSIZE) * 4;
                if (e < EE) {
                    int4 s4 = *reinterpret_cast<const int4*>(srcp + e);
                    int4 d4 = *reinterpret_cast<const int4*>(dstp + e);
                    float m0 = msg_base[s4.x] * ea[(size_t)(e + 0) * TT + t];
                    float m1 = msg_base[s4.y] * ea[(size_t)(e + 1) * TT + t];
                    float m2 = msg_base[s4.z] * ea[(size_t)(e + 2) * TT + t];
                    float m3 = msg_base[s4.w] * ea[(size_t)(e + 3) * TT + t];
                    atomicAdd(agg + d4.x, m0);
                    atomicAdd(agg + d4.y, m1);
                    atomicAdd(agg + d4.z, m2);
                    atomicAdd(agg + d4.w, m3);
                }
            }
        }
        grid.sync();

        // Node phase
        if (gid < NN) {
            float a = agg[gid];
            float x1v = fast_x ? xb[t * NN + gid] : x[(size_t)gid * 20 + 2 * t + 1];

            float uin[10];
            uin[0] = x1v;
#pragma unroll
            for (int k = 0; k < 8; ++k) uin[1 + k] = hid[k];
            uin[9] = a;

            float u1[32];
#pragma unroll
            for (int j = 0; j < 32; ++j) {
                float acc = s_m2b1[j];
#pragma unroll
                for (int i = 0; i < 10; ++i) acc += uin[i] * s_m2w1[i * 32 + j];
                u1[j] = reluf_(acc);
            }
#pragma unroll
            for (int k = 0; k < 8; ++k) {
                float acc = s_m2b2[k];
#pragma unroll
                for (int j = 0; j < 32; ++j) acc += u1[j] * s_m2w2[j * 8 + k];
                hid[k] = tanhf(reluf_(acc));
            }

            float o1[16];
#pragma unroll
            for (int l = 0; l < 16; ++l) {
                float acc = s_ob1[l];
#pragma unroll
                for (int k = 0; k < 8; ++k) acc += hid[k] * s_ow1[k * 16 + l];
                o1[l] = reluf_(acc);
            }
            float oo = s_ob2s;
#pragma unroll
            for (int l = 0; l < 16; ++l) oo += o1[l] * s_ow2[l];
            out[t * NN + gid] = sigmoidf_(oo);

            if (t < TT - 1) {
                float feat[9];
                feat[0] = fast_x ? xa[(t + 1) * NN + gid]
                                 : x[(size_t)gid * 20 + 2 * (t + 1)];
#pragma unroll
                for (int k = 0; k < 8; ++k) feat[1 + k] = hid[k];
                msg_base[gid] = mlp1_eval(feat, s_w1, s_b1, s_w2, s_b2, s_w3, s_b3s);
                agg[gid] = 0.0f;
            }
        }
        grid.sync();
    }
}

extern "C" void kernel_launch(void* const* d_in, const int* in_sizes, int n_in,
                              void* d_out, int out_size, void* d_ws, size_t ws_size,
                              hipStream_t stream) {
    (void)in_sizes; (void)n_in; (void)out_size;
    const float* x    = (const float*)d_in[0];
    const int*   ei   = (const int*)d_in[1];
    const float* ea   = (const float*)d_in[2];
    const float* m1w1 = (const float*)d_in[3];
    const float* m1b1 = (const float*)d_in[4];
    const float* m1w2 = (const float*)d_in[5];
    const float* m1b2 = (const float*)d_in[6];
    const float* m1w3 = (const float*)d_in[7];
    const float* m1b3 = (const float*)d_in[8];
    const float* m2w1 = (const float*)d_in[9];
    const float* m2b1 = (const float*)d_in[10];
    const float* m2w2 = (const float*)d_in[11];
    const float* m2b2 = (const float*)d_in[12];
    const float* ow1  = (const float*)d_in[13];
    const float* ob1  = (const float*)d_in[14];
    const float* ow2  = (const float*)d_in[15];
    const float* ob2  = (const float*)d_in[16];
    float* out = (float*)d_out;

    // workspace layout (floats):
    // [0,NN)            msg_base
    // [NN,2NN)          agg
    // [2NN, 2NN+T*NN)   xa (x[:, t, 0] transposed)
    // [...,  +T*NN)     xb (x[:, t, 1] transposed)
    // [..., +T*EE)      eaT (edge_attr transposed to [T][E])
    float* msg_base = (float*)d_ws;
    float* agg = msg_base + NN;
    float* xa  = agg + NN;
    float* xb  = xa + (size_t)TT * NN;
    float* eaT = xb + (size_t)TT * NN;

    size_t need_x  = ((size_t)2 * NN + (size_t)2 * TT * NN) * sizeof(float);
    size_t need_ea = need_x + (size_t)TT * EE * sizeof(float);
    int fast_x  = (ws_size >= need_x) ? 1 : 0;
    int fast_ea = (ws_size >= need_ea) ? 1 : 0;

    void* args[] = {
        (void*)&x, (void*)&ei, (void*)&ea,
        (void*)&m1w1, (void*)&m1b1, (void*)&m1w2, (void*)&m1b2,
        (void*)&m1w3, (void*)&m1b3,
        (void*)&m2w1, (void*)&m2b1, (void*)&m2w2, (void*)&m2b2,
        (void*)&ow1, (void*)&ob1, (void*)&ow2, (void*)&ob2,
        (void*)&out, (void*)&msg_base, (void*)&agg,
        (void*)&xa, (void*)&xb, (void*)&eaT,
        (void*)&fast_x, (void*)&fast_ea
    };
    hipLaunchCooperativeKernel((const void*)fused_kernel,
                               dim3(GRID_BLOCKS), dim3(BLOCK),
                               args, 0, stream);
}